// Round 1
// baseline (176.109 us; speedup 1.0000x reference)
//
#include <hip/hip_runtime.h>

#define Bm 8
#define Sm 4096
#define Hm 2048
#define Em 64
#define Tm (Bm*Sm)      // 32768 tokens
#define KSEL 640        // int(1.25 * 32768 / 64)

#define TM 64           // tokens per block in GEMM
#define KC 64           // K chunk
#define LDA 68          // padded LDS stride (floats)

typedef unsigned int u32;

__device__ __forceinline__ float4 ld4(const float* p) {
    return *reinterpret_cast<const float4*>(p);
}

// ---------------------------------------------------------------------------
// K1: router GEMM (fp32, chunked accumulation for accuracy) + softmax.
// grid = Tm/TM = 512 blocks x 256 threads.
// Writes probs [T][E] (row-major, = output #3) and optionally probsT [E][T].
// ---------------------------------------------------------------------------
__global__ __launch_bounds__(256) void k_router(
    const float* __restrict__ hid, const float* __restrict__ W,
    float* __restrict__ probs, float* __restrict__ probsT)
{
    __shared__ float As[TM][LDA];   // 17.4 KB
    __shared__ float Wt[KC][LDA];   // 17.4 KB (transposed: Wt[k][e])

    const int tid = threadIdx.x;
    const int t0 = blockIdx.x * TM;
    const int te = tid & 15;        // expert group (4 experts each)
    const int tm = tid >> 4;        // token group  (4 tokens each)
    const int lrow  = tid >> 2;     // 0..63 load row
    const int lpart = tid & 3;      // 16-float slice of the row

    float accT[4][4];
#pragma unroll
    for (int i = 0; i < 4; ++i)
#pragma unroll
        for (int j = 0; j < 4; ++j) accT[i][j] = 0.f;

    const float* aptr = hid + (size_t)(t0 + lrow) * Hm + lpart * 16;
    const float* wptr = W   + (size_t)lrow        * Hm + lpart * 16;

    for (int k0 = 0; k0 < Hm; k0 += KC) {
        float4 a[4], w[4];
#pragma unroll
        for (int c = 0; c < 4; ++c) a[c] = ld4(aptr + k0 + 4 * c);
#pragma unroll
        for (int c = 0; c < 4; ++c) w[c] = ld4(wptr + k0 + 4 * c);

        __syncthreads();   // previous chunk's LDS reads complete
#pragma unroll
        for (int c = 0; c < 4; ++c)
            *reinterpret_cast<float4*>(&As[lrow][lpart * 16 + 4 * c]) = a[c];
#pragma unroll
        for (int c = 0; c < 4; ++c) {
            const float wv[4] = { w[c].x, w[c].y, w[c].z, w[c].w };
#pragma unroll
            for (int u = 0; u < 4; ++u)
                Wt[lpart * 16 + 4 * c + u][lrow] = wv[u];
        }
        __syncthreads();

        float acc[4][4];
#pragma unroll
        for (int i = 0; i < 4; ++i)
#pragma unroll
            for (int j = 0; j < 4; ++j) acc[i][j] = 0.f;

#pragma unroll 2
        for (int kq = 0; kq < KC; kq += 4) {
            float4 av4[4], wv4[4];
#pragma unroll
            for (int i = 0; i < 4; ++i)
                av4[i] = *reinterpret_cast<const float4*>(&As[4 * tm + i][kq]);
#pragma unroll
            for (int u = 0; u < 4; ++u)
                wv4[u] = *reinterpret_cast<const float4*>(&Wt[kq + u][4 * te]);

            float A_[4][4];
#pragma unroll
            for (int i = 0; i < 4; ++i) {
                A_[i][0] = av4[i].x; A_[i][1] = av4[i].y;
                A_[i][2] = av4[i].z; A_[i][3] = av4[i].w;
            }
#pragma unroll
            for (int u = 0; u < 4; ++u) {
                const float4 w4 = wv4[u];
#pragma unroll
                for (int i = 0; i < 4; ++i) {
                    acc[i][0] = fmaf(A_[i][u], w4.x, acc[i][0]);
                    acc[i][1] = fmaf(A_[i][u], w4.y, acc[i][1]);
                    acc[i][2] = fmaf(A_[i][u], w4.z, acc[i][2]);
                    acc[i][3] = fmaf(A_[i][u], w4.w, acc[i][3]);
                }
            }
        }
#pragma unroll
        for (int i = 0; i < 4; ++i)
#pragma unroll
            for (int j = 0; j < 4; ++j) accT[i][j] += acc[i][j];
    }

    // ---- softmax over the 64 experts of each token ----
    __syncthreads();
#pragma unroll
    for (int i = 0; i < 4; ++i)
        *reinterpret_cast<float4*>(&As[4 * tm + i][4 * te]) =
            make_float4(accT[i][0], accT[i][1], accT[i][2], accT[i][3]);
    __syncthreads();

    const int tok = tid >> 2;   // 0..63 (4 consecutive lanes per token)
    const int q   = tid & 3;    // 16 experts each
    float v[16];
#pragma unroll
    for (int c = 0; c < 4; ++c) {
        float4 x = *reinterpret_cast<const float4*>(&As[tok][q * 16 + 4 * c]);
        v[4 * c + 0] = x.x; v[4 * c + 1] = x.y;
        v[4 * c + 2] = x.z; v[4 * c + 3] = x.w;
    }
    float mx = v[0];
#pragma unroll
    for (int c = 1; c < 16; ++c) mx = fmaxf(mx, v[c]);
    mx = fmaxf(mx, __shfl_xor(mx, 1, 4));
    mx = fmaxf(mx, __shfl_xor(mx, 2, 4));
    float s = 0.f;
#pragma unroll
    for (int c = 0; c < 16; ++c) { v[c] = expf(v[c] - mx); s += v[c]; }
    s += __shfl_xor(s, 1, 4);
    s += __shfl_xor(s, 2, 4);
    const float inv = 1.0f / s;
#pragma unroll
    for (int c = 0; c < 16; ++c) v[c] *= inv;

    const int t = t0 + tok;
    float* po = probs + (size_t)t * Em + q * 16;
#pragma unroll
    for (int c = 0; c < 4; ++c)
        *reinterpret_cast<float4*>(po + 4 * c) =
            make_float4(v[4 * c], v[4 * c + 1], v[4 * c + 2], v[4 * c + 3]);
    if (probsT) {
#pragma unroll
        for (int c = 0; c < 16; ++c)
            probsT[(size_t)(q * 16 + c) * Tm + t] = v[c];
    }
}

// ---------------------------------------------------------------------------
// K2: per-expert top-640 radix select (10/11/11 bits) + scatter.
// grid = 64 blocks (one expert each) x 1024 threads. Keys live in LDS (128 KB).
// ---------------------------------------------------------------------------
__device__ __forceinline__ void suffix_scan(u32* h, int nbins) {
    const int tid = threadIdx.x;
    for (int off = 1; off < nbins; off <<= 1) {
        u32 v0 = 0, v1 = 0;
        const int b0 = tid, b1 = tid + 1024;
        if (b0 < nbins) v0 = h[b0] + ((b0 + off) < nbins ? h[b0 + off] : 0u);
        if (b1 < nbins) v1 = h[b1] + ((b1 + off) < nbins ? h[b1 + off] : 0u);
        __syncthreads();
        if (b0 < nbins) h[b0] = v0;
        if (b1 < nbins) h[b1] = v1;
        __syncthreads();
    }
}

__global__ __launch_bounds__(1024) void k_select(
    const float* __restrict__ probsT, const float* __restrict__ probsRM,
    float* __restrict__ dispatch)
{
    __shared__ u32 keys[Tm];        // 128 KB
    __shared__ u32 hist[2048];      // 8 KB (also reused as tie list)
    __shared__ u32 sh_need[4];
    __shared__ u32 sh_bins[3];
    __shared__ u32 sh_ntie, sh_take, sh_nlist;

    const int tid = threadIdx.x;
    const int e = blockIdx.x;

    if (probsT) {
        const float4* src = reinterpret_cast<const float4*>(probsT + (size_t)e * Tm);
        for (int i = tid; i < Tm / 4; i += 1024) {
            float4 x = src[i];
            uint4 kk = make_uint4(__float_as_uint(x.x), __float_as_uint(x.y),
                                  __float_as_uint(x.z), __float_as_uint(x.w));
            *reinterpret_cast<uint4*>(&keys[4 * i]) = kk;
        }
    } else {
        for (int t = tid; t < Tm; t += 1024)
            keys[t] = __float_as_uint(probsRM[(size_t)t * Em + e]);
    }

    // ---- pass 1: bits [31:22], 1024 bins ----
    hist[tid] = 0;
    if (tid == 0) sh_need[0] = KSEL;
    __syncthreads();
    for (int t = tid; t < Tm; t += 1024)
        atomicAdd(&hist[keys[t] >> 22], 1u);
    __syncthreads();
    suffix_scan(hist, 1024);
    {
        const u32 need = sh_need[0];
        const int b = tid;
        if (b < 1024) {
            const u32 sb = hist[b];
            const u32 sa = (b + 1 < 1024) ? hist[b + 1] : 0u;
            if (sb >= need && sa < need) { sh_bins[0] = (u32)b; sh_need[1] = need - sa; }
        }
    }
    __syncthreads();
    const u32 b1 = sh_bins[0];

    // ---- pass 2: bits [21:11], 2048 bins ----
    hist[tid] = 0; hist[tid + 1024] = 0;
    __syncthreads();
    for (int t = tid; t < Tm; t += 1024) {
        const u32 k = keys[t];
        if ((k >> 22) == b1) atomicAdd(&hist[(k >> 11) & 0x7FFu], 1u);
    }
    __syncthreads();
    suffix_scan(hist, 2048);
    {
        const u32 need = sh_need[1];
#pragma unroll
        for (int r = 0; r < 2; ++r) {
            const int b = tid + r * 1024;
            const u32 sb = hist[b];
            const u32 sa = (b + 1 < 2048) ? hist[b + 1] : 0u;
            if (sb >= need && sa < need) { sh_bins[1] = (u32)b; sh_need[2] = need - sa; }
        }
    }
    __syncthreads();
    const u32 p2 = (b1 << 11) | sh_bins[1];

    // ---- pass 3: bits [10:0], 2048 bins ----
    hist[tid] = 0; hist[tid + 1024] = 0;
    __syncthreads();
    for (int t = tid; t < Tm; t += 1024) {
        const u32 k = keys[t];
        if ((k >> 11) == p2) atomicAdd(&hist[k & 0x7FFu], 1u);
    }
    __syncthreads();
    suffix_scan(hist, 2048);
    {
        const u32 need = sh_need[2];
#pragma unroll
        for (int r = 0; r < 2; ++r) {
            const int b = tid + r * 1024;
            const u32 sb = hist[b];
            const u32 sa = (b + 1 < 2048) ? hist[b + 1] : 0u;
            if (sb >= need && sa < need) {
                sh_bins[2] = (u32)b;
                sh_take = need - sa;      // ties (== Kstar) to include
                sh_ntie = sb - sa;        // total ties
            }
        }
    }
    __syncthreads();
    const u32 Kstar = (p2 << 11) | sh_bins[2];
    const u32 take = sh_take, ntie = sh_ntie;

    // ---- scatter ----
    if (ntie == take) {
        for (int t = tid; t < Tm; t += 1024) {
            const u32 k = keys[t];
            if (k >= Kstar)
                dispatch[(size_t)t * Em + e] = __uint_as_float(k);
        }
    } else {
        // rare: more ties than slots -> include lowest token indices first
        if (tid == 0) sh_nlist = 0;
        __syncthreads();
        for (int t = tid; t < Tm; t += 1024) {
            const u32 k = keys[t];
            if (k > Kstar) {
                dispatch[(size_t)t * Em + e] = __uint_as_float(k);
            } else if (k == Kstar) {
                const u32 idx = atomicAdd(&sh_nlist, 1u);
                if (idx < 2048u) hist[idx] = (u32)t;
            }
        }
        __syncthreads();
        const int n = (int)(sh_nlist < 2048u ? sh_nlist : 2048u);
        for (int i = tid; i < n; i += 1024) {
            const u32 t = hist[i];
            int r = 0;
            for (int j = 0; j < n; ++j) r += (hist[j] < t);
            if (r < (int)take)
                dispatch[(size_t)t * Em + e] = __uint_as_float(Kstar);
        }
    }
}

// ---------------------------------------------------------------------------
// K3: combine weights — one wave per token row of 64 experts.
// ---------------------------------------------------------------------------
__global__ __launch_bounds__(256) void k_combine(
    const float* __restrict__ dispatch, float* __restrict__ combine)
{
    const int wid = threadIdx.x >> 6;
    const int lane = threadIdx.x & 63;
    const int t = blockIdx.x * 4 + wid;
    const float d = dispatch[(size_t)t * Em + lane];
    float s = d;
#pragma unroll
    for (int off = 32; off > 0; off >>= 1) s += __shfl_xor(s, off, 64);
    combine[(size_t)t * Em + lane] = (s > 0.f) ? d / s : 0.f;
}

// ---------------------------------------------------------------------------
extern "C" void kernel_launch(void* const* d_in, const int* in_sizes, int n_in,
                              void* d_out, int out_size, void* d_ws, size_t ws_size,
                              hipStream_t stream) {
    const float* hid = (const float*)d_in[0];
    const float* W   = (const float*)d_in[1];
    float* out      = (float*)d_out;
    float* dispatch = out;
    float* combine  = out + (size_t)Tm * Em;
    float* probs    = out + 2 * (size_t)Tm * Em;
    float* probsT   = nullptr;
    if (ws_size >= sizeof(float) * (size_t)Tm * Em)
        probsT = (float*)d_ws;

    hipMemsetAsync(dispatch, 0, sizeof(float) * (size_t)Tm * Em, stream);
    k_router<<<Tm / TM, 256, 0, stream>>>(hid, W, probs, probsT);
    k_select<<<Em, 1024, 0, stream>>>(probsT, probs, dispatch);
    k_combine<<<Tm / 4, 256, 0, stream>>>(dispatch, combine);
}

// Round 2
// 161.102 us; speedup vs baseline: 1.0932x; 1.0932x over previous
//
#include <hip/hip_runtime.h>

#define Bm 8
#define Sm 4096
#define Hm 2048
#define Em 64
#define Tm (Bm*Sm)      // 32768 tokens
#define KSEL 640        // int(1.25 * 32768 / 64)
#define NCH 16          // chunks of 64 k per K-half

typedef unsigned int u32;

__device__ __forceinline__ float4 ld4(const float* p) {
    return *reinterpret_cast<const float4*>(p);
}

// ---------------------------------------------------------------------------
// K0: W [64][2048] -> Wt [2048][64] (one-time, LDS tile transpose)
// grid = 32 blocks x 256 threads.
// ---------------------------------------------------------------------------
__global__ __launch_bounds__(256) void k_wt(
    const float* __restrict__ W, float* __restrict__ Wt)
{
    __shared__ float T[64][65];
    const int tid = threadIdx.x;
    const int kb = blockIdx.x * 64;
    const int lc = tid & 63;
    const int lr = tid >> 6;
#pragma unroll
    for (int r = 0; r < 16; ++r) {
        const int e = r * 4 + lr;
        T[e][lc] = W[(size_t)e * Hm + kb + lc];
    }
    __syncthreads();
#pragma unroll
    for (int r = 0; r < 16; ++r) {
        const int kk = r * 4 + lr;
        Wt[(size_t)(kb + kk) * Em + lc] = T[lc][kk];
    }
}

// ---------------------------------------------------------------------------
// K1: router GEMM + softmax. grid = 512 blocks x 256 threads.
// Split-K x2: kg = tid>>7 handles K half. Thread tile 8 tok x 4 exp.
// A staged k-major in LDS (reg-staged transpose); Wt chunk staged linear.
// ---------------------------------------------------------------------------
__global__ __launch_bounds__(256, 4) void k_router(
    const float* __restrict__ hid, const float* __restrict__ Wt,
    float* __restrict__ probs, float* __restrict__ probsT)
{
    __shared__ float As[128 * 64];   // 32 KB, [k-row][token] (k-major)
    __shared__ float Ws[128 * 64];   // 32 KB, [k-row][expert]

    const int tid = threadIdx.x;
    const int t0 = blockIdx.x * 64;
    const int kg = tid >> 7;          // K group 0/1
    const int eg = tid & 15;          // expert quad
    const int tg = (tid >> 4) & 7;    // token octet
    const int stok = tid & 63;        // staging: token
    const int seg  = tid >> 6;        // staging: segment 0..3

    const float* ap = hid + (size_t)(t0 + stok) * Hm;

    float acc[8][4];
#pragma unroll
    for (int i = 0; i < 8; ++i)
#pragma unroll
        for (int j = 0; j < 4; ++j) acc[i][j] = 0.f;

    float4 ar[8];   // A prefetch regs (2 segments x 16 floats)

    // --- staging helpers ---
    auto loadA = [&](int c) {
#pragma unroll
        for (int s2 = 0; s2 < 2; ++s2) {
            const int s = seg + 4 * s2;
            const int g = s >> 2;
            const int o = (s & 3) * 16;
            const int base = g * 1024 + c * 64 + o;
#pragma unroll
            for (int u = 0; u < 4; ++u)
                ar[s2 * 4 + u] = ld4(ap + base + 4 * u);
        }
    };
    auto writeA = [&]() {
#pragma unroll
        for (int s2 = 0; s2 < 2; ++s2) {
            const int s = seg + 4 * s2;
            const int g = s >> 2;
            const int o = (s & 3) * 16;
#pragma unroll
            for (int u = 0; u < 4; ++u) {
                const int r0 = g * 64 + o + 4 * u;
                const float4 v = ar[s2 * 4 + u];
                As[(r0 + 0) * 64 + stok] = v.x;
                As[(r0 + 1) * 64 + stok] = v.y;
                As[(r0 + 2) * 64 + stok] = v.z;
                As[(r0 + 3) * 64 + stok] = v.w;
            }
        }
    };
    auto stageW = [&](int c) {
        const float* w0 = Wt + c * 4096;
#pragma unroll
        for (int u = 0; u < 8; ++u) {
            const int F = 4 * (tid + 256 * u);
            const float4 v = ld4(w0 + F + (u < 4 ? 0 : 61440));
            *reinterpret_cast<float4*>(&Ws[F]) = v;
        }
    };

    // prologue: stage chunk 0
    loadA(0);
    writeA();
    stageW(0);
    __syncthreads();

    const float* asb = As + kg * 4096 + 8 * tg;
    const float* wsb = Ws + kg * 4096 + 4 * eg;

    for (int c = 0; c < NCH; ++c) {
        if (c + 1 < NCH) loadA(c + 1);   // HBM latency hides under k-loop

#pragma unroll 8
        for (int kk = 0; kk < 64; ++kk) {
            const float4 a0 = ld4(asb + kk * 64);
            const float4 a1 = ld4(asb + kk * 64 + 4);
            const float4 w  = ld4(wsb + kk * 64);
            const float a[8] = { a0.x, a0.y, a0.z, a0.w,
                                 a1.x, a1.y, a1.z, a1.w };
#pragma unroll
            for (int i = 0; i < 8; ++i) {
                acc[i][0] = fmaf(a[i], w.x, acc[i][0]);
                acc[i][1] = fmaf(a[i], w.y, acc[i][1]);
                acc[i][2] = fmaf(a[i], w.z, acc[i][2]);
                acc[i][3] = fmaf(a[i], w.w, acc[i][3]);
            }
        }
        __syncthreads();     // all waves done reading As/Ws
        if (c + 1 < NCH) {
            writeA();
            stageW(c + 1);
            __syncthreads();
        }
    }

    // --- cross-group reduce (Rs aliases Ws, Ls aliases As; stride 68) ---
    float* Rs = Ws;
    float* Ls = As;
    if (kg == 1) {
#pragma unroll
        for (int i = 0; i < 8; ++i)
            *reinterpret_cast<float4*>(&Rs[(8 * tg + i) * 68 + 4 * eg]) =
                make_float4(acc[i][0], acc[i][1], acc[i][2], acc[i][3]);
    }
    __syncthreads();
    if (kg == 0) {
#pragma unroll
        for (int i = 0; i < 8; ++i) {
            const float4 o = ld4(&Rs[(8 * tg + i) * 68 + 4 * eg]);
            *reinterpret_cast<float4*>(&Ls[(8 * tg + i) * 68 + 4 * eg]) =
                make_float4(acc[i][0] + o.x, acc[i][1] + o.y,
                            acc[i][2] + o.z, acc[i][3] + o.w);
        }
    }
    __syncthreads();

    // --- softmax over 64 experts (4 lanes per token, 16 experts each) ---
    const int tok = tid >> 2;
    const int q   = tid & 3;
    float v[16];
#pragma unroll
    for (int c = 0; c < 4; ++c) {
        const float4 x = ld4(&Ls[tok * 68 + q * 16 + 4 * c]);
        v[4 * c + 0] = x.x; v[4 * c + 1] = x.y;
        v[4 * c + 2] = x.z; v[4 * c + 3] = x.w;
    }
    float mx = v[0];
#pragma unroll
    for (int c = 1; c < 16; ++c) mx = fmaxf(mx, v[c]);
    mx = fmaxf(mx, __shfl_xor(mx, 1, 4));
    mx = fmaxf(mx, __shfl_xor(mx, 2, 4));
    float s = 0.f;
#pragma unroll
    for (int c = 0; c < 16; ++c) { v[c] = expf(v[c] - mx); s += v[c]; }
    s += __shfl_xor(s, 1, 4);
    s += __shfl_xor(s, 2, 4);
    const float inv = 1.0f / s;
#pragma unroll
    for (int c = 0; c < 16; ++c) v[c] *= inv;

    const int t = t0 + tok;
    float* po = probs + (size_t)t * Em + q * 16;
#pragma unroll
    for (int c = 0; c < 4; ++c)
        *reinterpret_cast<float4*>(po + 4 * c) =
            make_float4(v[4 * c], v[4 * c + 1], v[4 * c + 2], v[4 * c + 3]);
    if (probsT) {
#pragma unroll
        for (int c = 0; c < 16; ++c)
            probsT[(size_t)(q * 16 + c) * Tm + t] = v[c];
    }
}

// ---------------------------------------------------------------------------
// K2: per-expert top-640 radix select (10/11/11 bits) + scatter.
// grid = 64 blocks (one expert each) x 1024 threads. Keys in LDS (128 KB).
// ---------------------------------------------------------------------------
__device__ __forceinline__ void suffix_scan(u32* h, int nbins) {
    const int tid = threadIdx.x;
    for (int off = 1; off < nbins; off <<= 1) {
        u32 v0 = 0, v1 = 0;
        const int b0 = tid, b1 = tid + 1024;
        if (b0 < nbins) v0 = h[b0] + ((b0 + off) < nbins ? h[b0 + off] : 0u);
        if (b1 < nbins) v1 = h[b1] + ((b1 + off) < nbins ? h[b1 + off] : 0u);
        __syncthreads();
        if (b0 < nbins) h[b0] = v0;
        if (b1 < nbins) h[b1] = v1;
        __syncthreads();
    }
}

__global__ __launch_bounds__(1024) void k_select(
    const float* __restrict__ probsT, const float* __restrict__ probsRM,
    float* __restrict__ dispatch)
{
    __shared__ u32 keys[Tm];        // 128 KB
    __shared__ u32 hist[2048];      // 8 KB (also reused as tie list)
    __shared__ u32 sh_need[4];
    __shared__ u32 sh_bins[3];
    __shared__ u32 sh_ntie, sh_take, sh_nlist;

    const int tid = threadIdx.x;
    const int e = blockIdx.x;

    if (probsT) {
        const float4* src = reinterpret_cast<const float4*>(probsT + (size_t)e * Tm);
        for (int i = tid; i < Tm / 4; i += 1024) {
            float4 x = src[i];
            uint4 kk = make_uint4(__float_as_uint(x.x), __float_as_uint(x.y),
                                  __float_as_uint(x.z), __float_as_uint(x.w));
            *reinterpret_cast<uint4*>(&keys[4 * i]) = kk;
        }
    } else {
        for (int t = tid; t < Tm; t += 1024)
            keys[t] = __float_as_uint(probsRM[(size_t)t * Em + e]);
    }

    // ---- pass 1: bits [31:22], 1024 bins ----
    hist[tid] = 0;
    if (tid == 0) sh_need[0] = KSEL;
    __syncthreads();
    for (int t = tid; t < Tm; t += 1024)
        atomicAdd(&hist[keys[t] >> 22], 1u);
    __syncthreads();
    suffix_scan(hist, 1024);
    {
        const u32 need = sh_need[0];
        const int b = tid;
        if (b < 1024) {
            const u32 sb = hist[b];
            const u32 sa = (b + 1 < 1024) ? hist[b + 1] : 0u;
            if (sb >= need && sa < need) { sh_bins[0] = (u32)b; sh_need[1] = need - sa; }
        }
    }
    __syncthreads();
    const u32 b1 = sh_bins[0];

    // ---- pass 2: bits [21:11], 2048 bins ----
    hist[tid] = 0; hist[tid + 1024] = 0;
    __syncthreads();
    for (int t = tid; t < Tm; t += 1024) {
        const u32 k = keys[t];
        if ((k >> 22) == b1) atomicAdd(&hist[(k >> 11) & 0x7FFu], 1u);
    }
    __syncthreads();
    suffix_scan(hist, 2048);
    {
        const u32 need = sh_need[1];
#pragma unroll
        for (int r = 0; r < 2; ++r) {
            const int b = tid + r * 1024;
            const u32 sb = hist[b];
            const u32 sa = (b + 1 < 2048) ? hist[b + 1] : 0u;
            if (sb >= need && sa < need) { sh_bins[1] = (u32)b; sh_need[2] = need - sa; }
        }
    }
    __syncthreads();
    const u32 p2 = (b1 << 11) | sh_bins[1];

    // ---- pass 3: bits [10:0], 2048 bins ----
    hist[tid] = 0; hist[tid + 1024] = 0;
    __syncthreads();
    for (int t = tid; t < Tm; t += 1024) {
        const u32 k = keys[t];
        if ((k >> 11) == p2) atomicAdd(&hist[k & 0x7FFu], 1u);
    }
    __syncthreads();
    suffix_scan(hist, 2048);
    {
        const u32 need = sh_need[2];
#pragma unroll
        for (int r = 0; r < 2; ++r) {
            const int b = tid + r * 1024;
            const u32 sb = hist[b];
            const u32 sa = (b + 1 < 2048) ? hist[b + 1] : 0u;
            if (sb >= need && sa < need) {
                sh_bins[2] = (u32)b;
                sh_take = need - sa;      // ties (== Kstar) to include
                sh_ntie = sb - sa;        // total ties
            }
        }
    }
    __syncthreads();
    const u32 Kstar = (p2 << 11) | sh_bins[2];
    const u32 take = sh_take, ntie = sh_ntie;

    // ---- scatter ----
    if (ntie == take) {
        for (int t = tid; t < Tm; t += 1024) {
            const u32 k = keys[t];
            if (k >= Kstar)
                dispatch[(size_t)t * Em + e] = __uint_as_float(k);
        }
    } else {
        // rare: more ties than slots -> include lowest token indices first
        if (tid == 0) sh_nlist = 0;
        __syncthreads();
        for (int t = tid; t < Tm; t += 1024) {
            const u32 k = keys[t];
            if (k > Kstar) {
                dispatch[(size_t)t * Em + e] = __uint_as_float(k);
            } else if (k == Kstar) {
                const u32 idx = atomicAdd(&sh_nlist, 1u);
                if (idx < 2048u) hist[idx] = (u32)t;
            }
        }
        __syncthreads();
        const int n = (int)(sh_nlist < 2048u ? sh_nlist : 2048u);
        for (int i = tid; i < n; i += 1024) {
            const u32 t = hist[i];
            int r = 0;
            for (int j = 0; j < n; ++j) r += (hist[j] < t);
            if (r < (int)take)
                dispatch[(size_t)t * Em + e] = __uint_as_float(Kstar);
        }
    }
}

// ---------------------------------------------------------------------------
// K3: combine weights — one wave per token row of 64 experts.
// ---------------------------------------------------------------------------
__global__ __launch_bounds__(256) void k_combine(
    const float* __restrict__ dispatch, float* __restrict__ combine)
{
    const int wid = threadIdx.x >> 6;
    const int lane = threadIdx.x & 63;
    const int t = blockIdx.x * 4 + wid;
    const float d = dispatch[(size_t)t * Em + lane];
    float s = d;
#pragma unroll
    for (int off = 32; off > 0; off >>= 1) s += __shfl_xor(s, off, 64);
    combine[(size_t)t * Em + lane] = (s > 0.f) ? d / s : 0.f;
}

// ---------------------------------------------------------------------------
extern "C" void kernel_launch(void* const* d_in, const int* in_sizes, int n_in,
                              void* d_out, int out_size, void* d_ws, size_t ws_size,
                              hipStream_t stream) {
    const float* hid = (const float*)d_in[0];
    const float* W   = (const float*)d_in[1];
    float* out      = (float*)d_out;
    float* dispatch = out;
    float* combine  = out + (size_t)Tm * Em;
    float* probs    = out + 2 * (size_t)Tm * Em;

    float* Wt = (float*)d_ws;                    // 512 KB (required)
    float* probsT = nullptr;                     // 8 MB (optional)
    const size_t wt_bytes = sizeof(float) * (size_t)Hm * Em;
    if (ws_size >= wt_bytes + sizeof(float) * (size_t)Tm * Em)
        probsT = (float*)((char*)d_ws + wt_bytes);

    hipMemsetAsync(dispatch, 0, sizeof(float) * (size_t)Tm * Em, stream);
    k_wt<<<Hm / 64, 256, 0, stream>>>(W, Wt);
    k_router<<<Tm / 64, 256, 0, stream>>>(hid, Wt, probs, probsT);
    k_select<<<Em, 1024, 0, stream>>>(probsT, probs, dispatch);
    k_combine<<<Tm / 4, 256, 0, stream>>>(dispatch, combine);
}